// Round 5
// baseline (376.263 us; speedup 1.0000x reference)
//
#include <hip/hip_runtime.h>
#include <hip/hip_fp16.h>

#define RAD 40
#define SEGF 64          // output rows per wave-strip
#define TX 128           // output cols per wave (scan domain 208 <= 256 = 64 lanes x 4)
#define HH 1024
#define WW 1024
#define NSTRIP (HH / SEGF)   // 16
#define NXT (WW / TX)        // 8

__device__ __forceinline__ float wscan64(float v, int lane) {
    #pragma unroll
    for (int d = 1; d < 64; d <<= 1) {
        float n = __shfl_up(v, d, 64);
        if (lane >= d) v += n;
    }
    return v;
}

// Swizzle: strips 2k,2k+1 of a column land 8 bids apart (same XCD under
// round-robin bid->XCD) so vertical-halo re-reads share an L2. Heuristic only.
__device__ __forceinline__ void decode_bid(int bid, int& c, int& x0, int& y0) {
    const int colid = bid >> 4;                    // [0, BC*NXT)
    const int sw = bid & 15;
    const int strip = ((sw & 7) << 1) | (sw >> 3); // bijection on [0,16)
    c = colid >> 3;                                // NXT == 8
    x0 = (colid & 7) * TX;
    y0 = strip * SEGF;
}

// Register-only horizontal box from per-lane inclusive prefixes.
// Lane l holds inclusive scan at domain cols 4l..4l+3 in ii[0..3].
// Output m in {0,1}: local col o=2l+m, domain d=o+40; box = incl[d+40]-incl[d-41].
// hi elem: even lane -> ii[m], odd -> ii[2+m]; lo elem: m=0: even->ii[3], odd->ii[1];
//                                              m=1: even->ii[0], odd->ii[2].
#define BOXF(ii, m, laneH, laneL, lod, odd, box) {                      \
    float he_ = __shfl(ii[(m)], laneH);                                 \
    float ho_ = __shfl(ii[2 + (m)], laneH);                             \
    float hv_ = (odd) ? ho_ : he_;                                      \
    float le_, lo_;                                                     \
    if ((m) == 0) { le_ = __shfl(ii[3], laneL); lo_ = __shfl(ii[1], laneL); } \
    else          { le_ = __shfl(ii[0], laneL); lo_ = __shfl(ii[2], laneL); } \
    float lv_ = (odd) ? lo_ : le_;                                      \
    if ((lod) < 0) lv_ = 0.f;                                           \
    box = hv_ - lv_; }

// ---------------------------------------------------------------------------
// K_A: one wave per (channel, x-tile, y-strip). Vertical sliding sums of
// I,p,Ip,II in registers; per-row register-only wave scan; writes a,b fp16x2.
// ---------------------------------------------------------------------------
__global__ __launch_bounds__(64, 4)
void fused_ab_kernel(const float* __restrict__ I, const float* __restrict__ p,
                     unsigned int* __restrict__ ab) {
    const int l = threadIdx.x;
    int c, x0, y0;
    decode_bid(blockIdx.x, c, x0, y0);
    const size_t plane = (size_t)c * (HH * WW);
    const int g1 = x0 - RAD + 4 * l;               // domain col of this lane (x4)
    const bool vld = (g1 >= 0) && (g1 < WW);
    const float* Irow = I + plane + g1;
    const float* Prow = p + plane + g1;

    float s0[4] = {0,0,0,0}, s1[4] = {0,0,0,0};
    float s2[4] = {0,0,0,0}, s3[4] = {0,0,0,0};

    auto ld = [&](const float* basep, int y) -> float4 {
        return vld ? *(const float4*)(basep + (size_t)y * WW)
                   : make_float4(0.f, 0.f, 0.f, 0.f);
    };
    auto accum = [&](const float4& a, const float4& b, float sg) {
        const float* av = (const float*)&a;
        const float* bv = (const float*)&b;
        #pragma unroll
        for (int k = 0; k < 4; ++k) {
            s0[k] += sg * av[k];
            s1[k] += sg * bv[k];
            s2[k] += sg * av[k] * bv[k];
            s3[k] += sg * av[k] * av[k];
        }
    };
    auto scan4 = [&](const float* sf, float* ii) {
        float c0 = sf[0];
        float c1 = c0 + sf[1];
        float c2 = c1 + sf[2];
        float c3 = c2 + sf[3];
        float u = wscan64(c3, l);
        float ex = u - c3;
        ii[0] = ex + c0; ii[1] = ex + c1; ii[2] = ex + c2; ii[3] = ex + c3;
    };

    // prime rows [max(y0-40,0), y0+40), batched 4-deep for MLP
    int yp0 = y0 - RAD; if (yp0 < 0) yp0 = 0;
    const int yp1 = y0 + RAD;                      // y0+RAD <= 1000 < HH always
    int y = yp0;
    for (; y + 4 <= yp1; y += 4) {
        float4 a0 = ld(Irow, y),     b0 = ld(Prow, y);
        float4 a1 = ld(Irow, y + 1), b1 = ld(Prow, y + 1);
        float4 a2 = ld(Irow, y + 2), b2 = ld(Prow, y + 2);
        float4 a3 = ld(Irow, y + 3), b3 = ld(Prow, y + 3);
        accum(a0, b0, 1.f); accum(a1, b1, 1.f);
        accum(a2, b2, 1.f); accum(a3, b3, 1.f);
    }
    for (; y < yp1; ++y) { float4 a = ld(Irow, y), b = ld(Prow, y); accum(a, b, 1.f); }

    float4 pA = ld(Irow, y0 + RAD), pB = ld(Prow, y0 + RAD);
    const bool odd = (l & 1) != 0;

    for (int yy = y0; yy < y0 + SEGF; ++yy) {
        if (yy + RAD < HH) accum(pA, pB, 1.f);

        // issue next add-row + this row's sub-row loads; consumed after scan
        const int yn = yy + 1 + RAD;
        const bool nh = (yn < HH) && (yy + 1 < y0 + SEGF);
        float4 nA = make_float4(0,0,0,0), nB = make_float4(0,0,0,0);
        if (nh) { nA = ld(Irow, yn); nB = ld(Prow, yn); }
        const int ys = yy - RAD;
        float4 sA = make_float4(0,0,0,0), sB = make_float4(0,0,0,0);
        if (ys >= 0) { sA = ld(Irow, ys); sB = ld(Prow, ys); }

        float i0[4], i1[4], i2[4], i3[4];
        scan4(s0, i0); scan4(s1, i1); scan4(s2, i2); scan4(s3, i3);

        const int cv_hi = (yy + RAD + 1 < HH) ? yy + RAD + 1 : HH;
        const int cv_lo = (ys > 0) ? ys : 0;
        const float cntV = (float)(cv_hi - cv_lo);

        unsigned int w0, w1;
        #pragma unroll
        for (int m = 0; m < 2; ++m) {
            const int laneH = (2 * l + m + 80) >> 2;
            const int lod = 2 * l + m - 1;
            const int laneL = (lod > 0) ? (lod >> 2) : 0;
            float bI, bp, bIp, bII;
            BOXF(i0, m, laneH, laneL, lod, odd, bI);
            BOXF(i1, m, laneH, laneL, lod, odd, bp);
            BOXF(i2, m, laneH, laneL, lod, odd, bIp);
            BOXF(i3, m, laneH, laneL, lod, odd, bII);
            const int go = x0 + 2 * l + m;
            int hlo = go - RAD;     if (hlo < 0)  hlo = 0;
            int hhi = go + RAD + 1; if (hhi > WW) hhi = WW;
            const float ic = __builtin_amdgcn_rcpf(cntV * (float)(hhi - hlo));
            const float mI = bI * ic, mp = bp * ic, mIp = bIp * ic, mII = bII * ic;
            const float cov = mIp - mI * mp;
            const float var = mII - mI * mI;
            const float aa = cov * __builtin_amdgcn_rcpf(var + 1e-3f);
            const float bb = mp - aa * mI;
            __half2 hh = __float22half2_rn(make_float2(aa, bb));
            (m == 0 ? w0 : w1) = *(unsigned int*)&hh;
        }
        *(uint2*)(ab + plane + (size_t)yy * WW + x0 + 2 * l) = make_uint2(w0, w1);

        if (ys >= 0) accum(sA, sB, -1.f);
        pA = nA; pB = nB;
    }
}

// ---------------------------------------------------------------------------
// K_B: same structure on packed fp16x2 {a,b}; epilogue out = mean_a*I + mean_b
// ---------------------------------------------------------------------------
__global__ __launch_bounds__(64, 4)
void fused_out_kernel(const unsigned int* __restrict__ ab, const float* __restrict__ I,
                      float* __restrict__ out) {
    const int l = threadIdx.x;
    int c, x0, y0;
    decode_bid(blockIdx.x, c, x0, y0);
    const size_t plane = (size_t)c * (HH * WW);
    const int g1 = x0 - RAD + 4 * l;
    const bool vld = (g1 >= 0) && (g1 < WW);
    const unsigned int* Arow = ab + plane + g1;

    float sA[4] = {0,0,0,0}, sB[4] = {0,0,0,0};

    struct ABV { float a[4]; float b[4]; };
    auto ldab = [&](int y) -> ABV {
        ABV r;
        uint4 q = vld ? *(const uint4*)(Arow + (size_t)y * WW) : make_uint4(0u,0u,0u,0u);
        const unsigned int* qw = (const unsigned int*)&q;
        #pragma unroll
        for (int k = 0; k < 4; ++k) {
            float2 f = __half22float2(*(const __half2*)&qw[k]);
            r.a[k] = f.x; r.b[k] = f.y;
        }
        return r;
    };
    auto accum = [&](const ABV& v, float sg) {
        #pragma unroll
        for (int k = 0; k < 4; ++k) { sA[k] += sg * v.a[k]; sB[k] += sg * v.b[k]; }
    };
    auto scan4 = [&](const float* sf, float* ii) {
        float c0 = sf[0];
        float c1 = c0 + sf[1];
        float c2 = c1 + sf[2];
        float c3 = c2 + sf[3];
        float u = wscan64(c3, l);
        float ex = u - c3;
        ii[0] = ex + c0; ii[1] = ex + c1; ii[2] = ex + c2; ii[3] = ex + c3;
    };

    int yp0 = y0 - RAD; if (yp0 < 0) yp0 = 0;
    const int yp1 = y0 + RAD;
    int y = yp0;
    for (; y + 4 <= yp1; y += 4) {
        ABV v0 = ldab(y), v1 = ldab(y + 1), v2 = ldab(y + 2), v3 = ldab(y + 3);
        accum(v0, 1.f); accum(v1, 1.f); accum(v2, 1.f); accum(v3, 1.f);
    }
    for (; y < yp1; ++y) { ABV v = ldab(y); accum(v, 1.f); }

    ABV pV = ldab(y0 + RAD);
    const bool odd = (l & 1) != 0;

    for (int yy = y0; yy < y0 + SEGF; ++yy) {
        if (yy + RAD < HH) accum(pV, 1.f);

        const int yn = yy + 1 + RAD;
        const bool nh = (yn < HH) && (yy + 1 < y0 + SEGF);
        ABV nV = {}, sV = {};
        if (nh) nV = ldab(yn);
        const int ys = yy - RAD;
        if (ys >= 0) sV = ldab(ys);
        const float2 Iv = *(const float2*)(I + plane + (size_t)yy * WW + x0 + 2 * l);

        float ia[4], ib[4];
        scan4(sA, ia); scan4(sB, ib);

        const int cv_hi = (yy + RAD + 1 < HH) ? yy + RAD + 1 : HH;
        const int cv_lo = (ys > 0) ? ys : 0;
        const float cntV = (float)(cv_hi - cv_lo);

        float o0, o1;
        #pragma unroll
        for (int m = 0; m < 2; ++m) {
            const int laneH = (2 * l + m + 80) >> 2;
            const int lod = 2 * l + m - 1;
            const int laneL = (lod > 0) ? (lod >> 2) : 0;
            float ba, bb;
            BOXF(ia, m, laneH, laneL, lod, odd, ba);
            BOXF(ib, m, laneH, laneL, lod, odd, bb);
            const int go = x0 + 2 * l + m;
            int hlo = go - RAD;     if (hlo < 0)  hlo = 0;
            int hhi = go + RAD + 1; if (hhi > WW) hhi = WW;
            const float ic = __builtin_amdgcn_rcpf(cntV * (float)(hhi - hlo));
            const float Ik = (m == 0) ? Iv.x : Iv.y;
            const float res = (ba * ic) * Ik + bb * ic;
            (m == 0 ? o0 : o1) = res;
        }
        *(float2*)(out + plane + (size_t)yy * WW + x0 + 2 * l) = make_float2(o0, o1);

        if (ys >= 0) accum(sV, -1.f);
        pV = nV;
    }
}

extern "C" void kernel_launch(void* const* d_in, const int* in_sizes, int n_in,
                              void* d_out, int out_size, void* d_ws, size_t ws_size,
                              hipStream_t stream) {
    const float* I = (const float*)d_in[0];
    const float* p = (const float*)d_in[1];
    float* out = (float*)d_out;

    const int N = in_sizes[0];           // B*C*H*W
    const int BC = N / (HH * WW);

    unsigned int* ab = (unsigned int*)d_ws;   // fp16x2 {a,b} per pixel (N uints)

    const int nblk = BC * NXT * NSTRIP;  // 12 * 8 * 16 = 1536 waves
    fused_ab_kernel<<<dim3(nblk), 64, 0, stream>>>(I, p, ab);
    fused_out_kernel<<<dim3(nblk), 64, 0, stream>>>(ab, I, out);
}

// Round 7
// 373.456 us; speedup vs baseline: 1.0075x; 1.0075x over previous
//
#include <hip/hip_runtime.h>
#include <hip/hip_fp16.h>

#define RAD 40
#define SEGF 16          // output rows per wave-strip (small => many waves)
#define TX 128           // output cols per wave (scan domain 208 <= 256 = 64x4)
#define HH 1024
#define WW 1024
#define NSTRIP (HH / SEGF)   // 64
#define NXT (WW / TX)        // 8

__device__ __forceinline__ float wscan64(float v, int lane) {
    #pragma unroll
    for (int d = 1; d < 64; d <<= 1) {
        float n = __shfl_up(v, d, 64);
        if (lane >= d) v += n;
    }
    return v;
}

__device__ __forceinline__ void decode_bid(int bid, int& c, int& x0, int& y0) {
    c = bid >> 9;                 // / (NXT*NSTRIP) = /512
    x0 = ((bid >> 6) & 7) * TX;   // NXT = 8
    y0 = (bid & 63) * SEGF;       // NSTRIP = 64
}

// Register-only horizontal box from per-lane inclusive prefixes.
// Lane l holds inclusive scan at domain cols 4l..4l+3 in ii[0..3].
// Output m in {0,1}: local col o=2l+m, domain d=o+40; box = incl[d+40]-incl[d-41].
#define BOXF(ii, m, laneH, laneL, lod, odd, box) {                      \
    float he_ = __shfl(ii[(m)], laneH);                                 \
    float ho_ = __shfl(ii[2 + (m)], laneH);                             \
    float hv_ = (odd) ? ho_ : he_;                                      \
    float le_, lo_;                                                     \
    if ((m) == 0) { le_ = __shfl(ii[3], laneL); lo_ = __shfl(ii[1], laneL); } \
    else          { le_ = __shfl(ii[0], laneL); lo_ = __shfl(ii[2], laneL); } \
    float lv_ = (odd) ? lo_ : le_;                                      \
    if ((lod) < 0) lv_ = 0.f;                                           \
    box = hv_ - lv_; }

// ---------------------------------------------------------------------------
// K_A: one wave per (channel, x-tile, y-strip). Vertical sliding sums of
// I,p,Ip,II in registers; per-row register-only wave scan; writes a,b fp16x2.
// ---------------------------------------------------------------------------
__global__ __launch_bounds__(64)
void fused_ab_kernel(const float* __restrict__ I, const float* __restrict__ p,
                     unsigned int* __restrict__ ab) {
    const int l = threadIdx.x;
    int c, x0, y0;
    decode_bid(blockIdx.x, c, x0, y0);
    const size_t plane = (size_t)c * (HH * WW);
    const int g1 = x0 - RAD + 4 * l;               // domain col of this lane (x4)
    const bool vld = (g1 >= 0) && (g1 < WW);
    const float* Irow = I + plane + g1;
    const float* Prow = p + plane + g1;

    float s0[4] = {0,0,0,0}, s1[4] = {0,0,0,0};
    float s2[4] = {0,0,0,0}, s3[4] = {0,0,0,0};

    auto ld = [&](const float* basep, int y) -> float4 {
        return vld ? *(const float4*)(basep + (size_t)y * WW)
                   : make_float4(0.f, 0.f, 0.f, 0.f);
    };
    auto accum = [&](const float4& a, const float4& b, float sg) {
        const float* av = (const float*)&a;
        const float* bv = (const float*)&b;
        #pragma unroll
        for (int k = 0; k < 4; ++k) {
            s0[k] += sg * av[k];
            s1[k] += sg * bv[k];
            s2[k] += sg * av[k] * bv[k];
            s3[k] += sg * av[k] * av[k];
        }
    };
    auto scan4 = [&](const float* sf, float* ii) {
        float c0 = sf[0];
        float c1 = c0 + sf[1];
        float c2 = c1 + sf[2];
        float c3 = c2 + sf[3];
        float u = wscan64(c3, l);
        float ex = u - c3;
        ii[0] = ex + c0; ii[1] = ex + c1; ii[2] = ex + c2; ii[3] = ex + c3;
    };

    // prime rows [max(y0-40,0), min(y0+40,H)), batched 8-deep
    int yp0 = y0 - RAD; if (yp0 < 0) yp0 = 0;
    int yp1 = y0 + RAD; if (yp1 > HH) yp1 = HH;   // CLAMP (R5 bug: was unclamped)
    int y = yp0;
    for (; y + 8 <= yp1; y += 8) {
        float4 a0 = ld(Irow, y),     b0 = ld(Prow, y);
        float4 a1 = ld(Irow, y + 1), b1 = ld(Prow, y + 1);
        float4 a2 = ld(Irow, y + 2), b2 = ld(Prow, y + 2);
        float4 a3 = ld(Irow, y + 3), b3 = ld(Prow, y + 3);
        float4 a4 = ld(Irow, y + 4), b4 = ld(Prow, y + 4);
        float4 a5 = ld(Irow, y + 5), b5 = ld(Prow, y + 5);
        float4 a6 = ld(Irow, y + 6), b6 = ld(Prow, y + 6);
        float4 a7 = ld(Irow, y + 7), b7 = ld(Prow, y + 7);
        accum(a0, b0, 1.f); accum(a1, b1, 1.f);
        accum(a2, b2, 1.f); accum(a3, b3, 1.f);
        accum(a4, b4, 1.f); accum(a5, b5, 1.f);
        accum(a6, b6, 1.f); accum(a7, b7, 1.f);
    }
    for (; y < yp1; ++y) { float4 a = ld(Irow, y), b = ld(Prow, y); accum(a, b, 1.f); }

    float4 pA = make_float4(0,0,0,0), pB = make_float4(0,0,0,0);
    if (y0 + RAD < HH) { pA = ld(Irow, y0 + RAD); pB = ld(Prow, y0 + RAD); }
    const bool odd = (l & 1) != 0;

    for (int yy = y0; yy < y0 + SEGF; ++yy) {
        if (yy + RAD < HH) accum(pA, pB, 1.f);

        // issue next add-row + this row's sub-row loads; consumed after scan
        const int yn = yy + 1 + RAD;
        const bool nh = (yn < HH) && (yy + 1 < y0 + SEGF);
        float4 nA = make_float4(0,0,0,0), nB = make_float4(0,0,0,0);
        if (nh) { nA = ld(Irow, yn); nB = ld(Prow, yn); }
        const int ys = yy - RAD;
        float4 sA = make_float4(0,0,0,0), sB = make_float4(0,0,0,0);
        if (ys >= 0) { sA = ld(Irow, ys); sB = ld(Prow, ys); }

        float i0[4], i1[4], i2[4], i3[4];
        scan4(s0, i0); scan4(s1, i1); scan4(s2, i2); scan4(s3, i3);

        const int cv_hi = (yy + RAD + 1 < HH) ? yy + RAD + 1 : HH;
        const int cv_lo = (ys > 0) ? ys : 0;
        const float cntV = (float)(cv_hi - cv_lo);

        unsigned int w0, w1;
        #pragma unroll
        for (int m = 0; m < 2; ++m) {
            const int laneH = (2 * l + m + 80) >> 2;
            const int lod = 2 * l + m - 1;
            const int laneL = (lod > 0) ? (lod >> 2) : 0;
            float bI, bp, bIp, bII;
            BOXF(i0, m, laneH, laneL, lod, odd, bI);
            BOXF(i1, m, laneH, laneL, lod, odd, bp);
            BOXF(i2, m, laneH, laneL, lod, odd, bIp);
            BOXF(i3, m, laneH, laneL, lod, odd, bII);
            const int go = x0 + 2 * l + m;
            int hlo = go - RAD;     if (hlo < 0)  hlo = 0;
            int hhi = go + RAD + 1; if (hhi > WW) hhi = WW;
            const float ic = __builtin_amdgcn_rcpf(cntV * (float)(hhi - hlo));
            const float mI = bI * ic, mp = bp * ic, mIp = bIp * ic, mII = bII * ic;
            const float cov = mIp - mI * mp;
            const float var = mII - mI * mI;
            const float aa = cov * __builtin_amdgcn_rcpf(var + 1e-3f);
            const float bb = mp - aa * mI;
            __half2 hh = __float22half2_rn(make_float2(aa, bb));
            (m == 0 ? w0 : w1) = *(unsigned int*)&hh;
        }
        *(uint2*)(ab + plane + (size_t)yy * WW + x0 + 2 * l) = make_uint2(w0, w1);

        if (ys >= 0) accum(sA, sB, -1.f);
        pA = nA; pB = nB;
    }
}

// ---------------------------------------------------------------------------
// K_B: same structure on packed fp16x2 {a,b}; epilogue out = mean_a*I + mean_b
// ---------------------------------------------------------------------------
__global__ __launch_bounds__(64)
void fused_out_kernel(const unsigned int* __restrict__ ab, const float* __restrict__ I,
                      float* __restrict__ out) {
    const int l = threadIdx.x;
    int c, x0, y0;
    decode_bid(blockIdx.x, c, x0, y0);
    const size_t plane = (size_t)c * (HH * WW);
    const int g1 = x0 - RAD + 4 * l;
    const bool vld = (g1 >= 0) && (g1 < WW);
    const unsigned int* Arow = ab + plane + g1;

    float sA[4] = {0,0,0,0}, sB[4] = {0,0,0,0};

    struct ABV { float a[4]; float b[4]; };
    auto ldab = [&](int y) -> ABV {
        ABV r;
        uint4 q = vld ? *(const uint4*)(Arow + (size_t)y * WW) : make_uint4(0u,0u,0u,0u);
        const unsigned int* qw = (const unsigned int*)&q;
        #pragma unroll
        for (int k = 0; k < 4; ++k) {
            float2 f = __half22float2(*(const __half2*)&qw[k]);
            r.a[k] = f.x; r.b[k] = f.y;
        }
        return r;
    };
    auto accum = [&](const ABV& v, float sg) {
        #pragma unroll
        for (int k = 0; k < 4; ++k) { sA[k] += sg * v.a[k]; sB[k] += sg * v.b[k]; }
    };
    auto scan4 = [&](const float* sf, float* ii) {
        float c0 = sf[0];
        float c1 = c0 + sf[1];
        float c2 = c1 + sf[2];
        float c3 = c2 + sf[3];
        float u = wscan64(c3, l);
        float ex = u - c3;
        ii[0] = ex + c0; ii[1] = ex + c1; ii[2] = ex + c2; ii[3] = ex + c3;
    };

    int yp0 = y0 - RAD; if (yp0 < 0) yp0 = 0;
    int yp1 = y0 + RAD; if (yp1 > HH) yp1 = HH;   // CLAMP (R5 bug: was unclamped)
    int y = yp0;
    for (; y + 8 <= yp1; y += 8) {
        ABV v0 = ldab(y),     v1 = ldab(y + 1), v2 = ldab(y + 2), v3 = ldab(y + 3);
        ABV v4 = ldab(y + 4), v5 = ldab(y + 5), v6 = ldab(y + 6), v7 = ldab(y + 7);
        accum(v0, 1.f); accum(v1, 1.f); accum(v2, 1.f); accum(v3, 1.f);
        accum(v4, 1.f); accum(v5, 1.f); accum(v6, 1.f); accum(v7, 1.f);
    }
    for (; y < yp1; ++y) { ABV v = ldab(y); accum(v, 1.f); }

    ABV pV = {};
    if (y0 + RAD < HH) pV = ldab(y0 + RAD);
    const bool odd = (l & 1) != 0;

    for (int yy = y0; yy < y0 + SEGF; ++yy) {
        if (yy + RAD < HH) accum(pV, 1.f);

        const int yn = yy + 1 + RAD;
        const bool nh = (yn < HH) && (yy + 1 < y0 + SEGF);
        ABV nV = {}, sV = {};
        if (nh) nV = ldab(yn);
        const int ys = yy - RAD;
        if (ys >= 0) sV = ldab(ys);
        const float2 Iv = *(const float2*)(I + plane + (size_t)yy * WW + x0 + 2 * l);

        float ia[4], ib[4];
        scan4(sA, ia); scan4(sB, ib);

        const int cv_hi = (yy + RAD + 1 < HH) ? yy + RAD + 1 : HH;
        const int cv_lo = (ys > 0) ? ys : 0;
        const float cntV = (float)(cv_hi - cv_lo);

        float o0, o1;
        #pragma unroll
        for (int m = 0; m < 2; ++m) {
            const int laneH = (2 * l + m + 80) >> 2;
            const int lod = 2 * l + m - 1;
            const int laneL = (lod > 0) ? (lod >> 2) : 0;
            float ba, bb;
            BOXF(ia, m, laneH, laneL, lod, odd, ba);
            BOXF(ib, m, laneH, laneL, lod, odd, bb);
            const int go = x0 + 2 * l + m;
            int hlo = go - RAD;     if (hlo < 0)  hlo = 0;
            int hhi = go + RAD + 1; if (hhi > WW) hhi = WW;
            const float ic = __builtin_amdgcn_rcpf(cntV * (float)(hhi - hlo));
            const float Ik = (m == 0) ? Iv.x : Iv.y;
            const float res = (ba * ic) * Ik + bb * ic;
            (m == 0 ? o0 : o1) = res;
        }
        *(float2*)(out + plane + (size_t)yy * WW + x0 + 2 * l) = make_float2(o0, o1);

        if (ys >= 0) accum(sV, -1.f);
        pV = nV;
    }
}

extern "C" void kernel_launch(void* const* d_in, const int* in_sizes, int n_in,
                              void* d_out, int out_size, void* d_ws, size_t ws_size,
                              hipStream_t stream) {
    const float* I = (const float*)d_in[0];
    const float* p = (const float*)d_in[1];
    float* out = (float*)d_out;

    const int N = in_sizes[0];           // B*C*H*W
    const int BC = N / (HH * WW);

    unsigned int* ab = (unsigned int*)d_ws;   // fp16x2 {a,b} per pixel (N uints)

    const int nblk = BC * NXT * NSTRIP;  // 12 * 8 * 64 = 6144 waves
    fused_ab_kernel<<<dim3(nblk), 64, 0, stream>>>(I, p, ab);
    fused_out_kernel<<<dim3(nblk), 64, 0, stream>>>(ab, I, out);
}